// Round 1
// 448.672 us; speedup vs baseline: 1.0532x; 1.0532x over previous
//
#include <hip/hip_runtime.h>
#include <cstddef>

// EdgeAttention: fused Sobel-edge -> depthwise3x3 -> BN(eval) -> ReLU
// B=16, C=256, H=128, W=128, fp32.
// R4: zero-LDS register sliding-window. One wave owns a 64-row strip of one
// (b,c) image; 64 lanes x float2 = full 128-col row. Column halos come from
// neighbor lanes via __shfl (ds_bpermute: conflict-free crossbar). No LDS
// tiles, no __syncthreads, no 8-way-conflicted scalar halo reads (the 6.1e7
// SQ_LDS_BANK_CONFLICT cycles of R3), no vertical halo re-staging.

#define BB 16
#define CC 256
#define HH 128
#define WW 128
#define RSTRIP 64                 // rows per wave strip
#define NSTRIP (HH / RSTRIP)      // 2 strips per (b,c) image
#define EPS 1e-5f

struct DS { float dA, dB, sA, sB; };   // per-row Sobel row-combos
struct ER { float el, eA, eB, er; };   // edge row: left halo, e0, e1, right halo

__device__ __forceinline__ void xrow_load(const float* __restrict__ xp, int j,
                                          int lane, float& a0, float& a1) {
    if ((unsigned)j < (unsigned)HH) {
        const float2 v = *(const float2*)(xp + (size_t)j * WW + (lane << 1));
        a0 = v.x; a1 = v.y;
    } else {
        a0 = 0.f; a1 = 0.f;
    }
}

// Horizontal Sobel combos for one x-row. Lane i holds cols 2i, 2i+1.
//   dX = (right - left), sX = (left + 2*center + right)
__device__ __forceinline__ DS make_ds(float a0, float a1, int lane) {
    float xl = __shfl(a1, lane - 1, 64);   // col 2i-1 (lane i-1's a1)
    float xr = __shfl(a0, lane + 1, 64);   // col 2i+2 (lane i+1's a0)
    xl = (lane == 0)  ? 0.f : xl;          // image left pad
    xr = (lane == 63) ? 0.f : xr;          // image right pad
    DS d;
    d.dA = a1 - xl;
    d.dB = xr - a0;
    d.sA = xl + 2.f * a0 + a1;
    d.sB = a0 + 2.f * a1 + xr;
    return d;
}

// Edge row k from ds rows k-1 (p), k (q), k+1 (t).
__device__ __forceinline__ ER make_edge(const DS& p, const DS& q, const DS& t,
                                        int lane) {
    float gxA = p.dA + 2.f * q.dA + t.dA;
    float gxB = p.dB + 2.f * q.dB + t.dB;
    float gyA = t.sA - p.sA;
    float gyB = t.sB - p.sB;
    ER e;
    e.eA = 0.5f * (fabsf(gxA) + fabsf(gyA));
    e.eB = 0.5f * (fabsf(gxB) + fabsf(gyB));
    float el = __shfl(e.eB, lane - 1, 64); // edge col 2i-1
    float er = __shfl(e.eA, lane + 1, 64); // edge col 2i+2
    e.el = (lane == 0)  ? 0.f : el;
    e.er = (lane == 63) ? 0.f : er;
    return e;
}

__global__ __launch_bounds__(256) void edge_attn_reg(
    const float* __restrict__ x,
    const float* __restrict__ dw,
    const float* __restrict__ gamma,
    const float* __restrict__ beta,
    const float* __restrict__ mean,
    const float* __restrict__ var,
    float* __restrict__ out)
{
    const int lane = threadIdx.x & 63;
    const int wid  = (blockIdx.x << 2) + (threadIdx.x >> 6); // global wave id
    const int bc   = wid >> 1;                 // b*C + c   (NSTRIP == 2)
    const int y0   = (wid & 1) * RSTRIP;
    const int c    = bc & (CC - 1);

    const float* __restrict__ xp = x   + (size_t)bc * (HH * WW);
    float* __restrict__       op = out + (size_t)bc * (HH * WW);

    const float* __restrict__ wp = dw + c * 9;
    const float w0 = wp[0], w1 = wp[1], w2 = wp[2];
    const float w3 = wp[3], w4 = wp[4], w5 = wp[5];
    const float w6 = wp[6], w7 = wp[7], w8 = wp[8];
    const float inv  = gamma[c] / sqrtf(var[c] + EPS);
    const float bias = beta[c] - mean[c] * inv;

    // ---- prologue: x rows y0-2 .. y0+2 -> ds rows; edge rows y0-1, y0 ----
    float ta0, ta1, tb0, tb1, tc0, tc1, td0, td1, xa, xb;
    xrow_load(xp, y0 - 2, lane, ta0, ta1);
    xrow_load(xp, y0 - 1, lane, tb0, tb1);
    xrow_load(xp, y0,     lane, tc0, tc1);
    xrow_load(xp, y0 + 1, lane, td0, td1);
    xrow_load(xp, y0 + 2, lane, xa, xb);       // preloaded for iter r = y0

    DS dsA = make_ds(ta0, ta1, lane);          // row y0-2
    DS dsB = make_ds(tb0, tb1, lane);          // row y0-1
    DS d0  = make_ds(tc0, tc1, lane);          // row y0
    DS d1  = make_ds(td0, td1, lane);          // row y0+1

    ER e_m;                                    // edge row y0-1 (zero pad at top)
    if (y0 > 0) e_m = make_edge(dsA, dsB, d0, lane);
    else        { e_m.el = e_m.eA = e_m.eB = e_m.er = 0.f; }
    ER e_c = make_edge(dsB, d0, d1, lane);     // edge row y0

    // last x row this strip ever needs is y0+RSTRIP+1
    const int jlim = (y0 + RSTRIP + 1 < HH) ? (y0 + RSTRIP + 1) : (HH - 1);

    // ---- steady state: 1 load, 4 shuffles, ~45 VALU, 1 store per row ----
    for (int r = y0; r < y0 + RSTRIP; ++r) {
        // issue next row's load first (consumed next iteration)
        float na, nb;
        int j = r + 3;
        if (j <= jlim) xrow_load(xp, j, lane, na, nb);
        else           { na = 0.f; nb = 0.f; }

        DS d2 = make_ds(xa, xb, lane);         // row r+2 (loaded last iter)

        ER e_p;                                 // edge row r+1 (zero pad at bottom)
        if (r + 1 < HH) e_p = make_edge(d0, d1, d2, lane);
        else            { e_p.el = e_p.eA = e_p.eB = e_p.er = 0.f; }

        float o0 = w0 * e_m.el + w1 * e_m.eA + w2 * e_m.eB
                 + w3 * e_c.el + w4 * e_c.eA + w5 * e_c.eB
                 + w6 * e_p.el + w7 * e_p.eA + w8 * e_p.eB;
        float o1 = w0 * e_m.eA + w1 * e_m.eB + w2 * e_m.er
                 + w3 * e_c.eA + w4 * e_c.eB + w5 * e_c.er
                 + w6 * e_p.eA + w7 * e_p.eB + w8 * e_p.er;
        o0 = fmaxf(o0 * inv + bias, 0.f);
        o1 = fmaxf(o1 * inv + bias, 0.f);
        *(float2*)(op + (size_t)r * WW + (lane << 1)) = make_float2(o0, o1);

        // rotate rings (all named regs — static, no scratch)
        d0 = d1; d1 = d2;
        e_m = e_c; e_c = e_p;
        xa = na; xb = nb;
    }
}

extern "C" void kernel_launch(void* const* d_in, const int* in_sizes, int n_in,
                              void* d_out, int out_size, void* d_ws, size_t ws_size,
                              hipStream_t stream) {
    const float* x     = (const float*)d_in[0];
    const float* dw    = (const float*)d_in[1];
    const float* gamma = (const float*)d_in[2];
    const float* beta  = (const float*)d_in[3];
    const float* mean  = (const float*)d_in[4];
    const float* var   = (const float*)d_in[5];
    float* out = (float*)d_out;

    // 16*256 images * 2 strips = 8192 waves -> 2048 blocks of 4 waves
    const int nblocks = (BB * CC * NSTRIP) / 4;
    edge_attn_reg<<<nblocks, 256, 0, stream>>>(x, dw, gamma, beta, mean, var, out);
}

// Round 2
// 445.062 us; speedup vs baseline: 1.0618x; 1.0081x over previous
//
#include <hip/hip_runtime.h>
#include <cstddef>

// EdgeAttention: fused Sobel-edge -> depthwise3x3 -> BN(eval) -> ReLU
// B=16, C=256, H=128, W=128, fp32.
// R5: register sliding-window (R4) + deep software pipeline:
//  - 2-row prefetch ring (load row r+4 at iter r) -> ~2 iters of vmcnt slack
//  - branch-free steady loop (boundary rows peeled into prologue/epilogue)
//  - #pragma unroll 4 so 2-4 independent global_load_dwordx2 stay in flight
// Theory: R4 was memory-latency-bound (1-row prefetch ~800 cyc tolerance vs
// ~900 cyc HBM latency); this gets load clustering + counted vmcnt waits.

#define BB 16
#define CC 256
#define HH 128
#define WW 128
#define RSTRIP 64                 // rows per wave strip
#define NSTRIP (HH / RSTRIP)      // 2 strips per (b,c) image
#define EPS 1e-5f

struct DS { float dA, dB, sA, sB; };   // per-row Sobel row-combos
struct ER { float el, eA, eB, er; };   // edge row: left halo, e0, e1, right halo

__device__ __forceinline__ void xrow_load(const float* __restrict__ xp, int j,
                                          int lane, float& a0, float& a1) {
    if ((unsigned)j < (unsigned)HH) {
        const float2 v = *(const float2*)(xp + (size_t)j * WW + (lane << 1));
        a0 = v.x; a1 = v.y;
    } else {
        a0 = 0.f; a1 = 0.f;
    }
}

// Horizontal Sobel combos for one x-row. Lane i holds cols 2i, 2i+1.
//   dX = (right - left), sX = (left + 2*center + right)
__device__ __forceinline__ DS make_ds(float a0, float a1, int lane) {
    float xl = __shfl(a1, lane - 1, 64);   // col 2i-1 (lane i-1's a1)
    float xr = __shfl(a0, lane + 1, 64);   // col 2i+2 (lane i+1's a0)
    xl = (lane == 0)  ? 0.f : xl;          // image left pad
    xr = (lane == 63) ? 0.f : xr;          // image right pad
    DS d;
    d.dA = a1 - xl;
    d.dB = xr - a0;
    d.sA = xl + 2.f * a0 + a1;
    d.sB = a0 + 2.f * a1 + xr;
    return d;
}

// Edge row k from ds rows k-1 (p), k (q), k+1 (t).
__device__ __forceinline__ ER make_edge(const DS& p, const DS& q, const DS& t,
                                        int lane) {
    float gxA = p.dA + 2.f * q.dA + t.dA;
    float gxB = p.dB + 2.f * q.dB + t.dB;
    float gyA = t.sA - p.sA;
    float gyB = t.sB - p.sB;
    ER e;
    e.eA = 0.5f * (fabsf(gxA) + fabsf(gyA));
    e.eB = 0.5f * (fabsf(gxB) + fabsf(gyB));
    float el = __shfl(e.eB, lane - 1, 64); // edge col 2i-1
    float er = __shfl(e.eA, lane + 1, 64); // edge col 2i+2
    e.el = (lane == 0)  ? 0.f : el;
    e.er = (lane == 63) ? 0.f : er;
    return e;
}

__global__ __launch_bounds__(256) void edge_attn_reg(
    const float* __restrict__ x,
    const float* __restrict__ dw,
    const float* __restrict__ gamma,
    const float* __restrict__ beta,
    const float* __restrict__ mean,
    const float* __restrict__ var,
    float* __restrict__ out)
{
    const int lane = threadIdx.x & 63;
    const int wid  = (blockIdx.x << 2) + (threadIdx.x >> 6); // global wave id
    const int bc   = wid >> 1;                 // b*C + c   (NSTRIP == 2)
    const int y0   = (wid & 1) * RSTRIP;
    const int c    = bc & (CC - 1);

    const float* __restrict__ xp = x   + (size_t)bc * (HH * WW);
    float* __restrict__       op = out + (size_t)bc * (HH * WW);

    const float* __restrict__ wp = dw + c * 9;
    const float w0 = wp[0], w1 = wp[1], w2 = wp[2];
    const float w3 = wp[3], w4 = wp[4], w5 = wp[5];
    const float w6 = wp[6], w7 = wp[7], w8 = wp[8];
    const float inv  = gamma[c] / sqrtf(var[c] + EPS);
    const float bias = beta[c] - mean[c] * inv;

    // ---- prologue: x rows y0-2 .. y0+3; ds rows; edge rows y0-1, y0 ----
    float p0a, p0b, p1a, p1b, p2a, p2b, p3a, p3b;
    float xa, xb;   // x row r+2 at loop head
    float ya, yb;   // x row r+3 at loop head
    xrow_load(xp, y0 - 2, lane, p0a, p0b);
    xrow_load(xp, y0 - 1, lane, p1a, p1b);
    xrow_load(xp, y0,     lane, p2a, p2b);
    xrow_load(xp, y0 + 1, lane, p3a, p3b);
    xrow_load(xp, y0 + 2, lane, xa, xb);
    xrow_load(xp, y0 + 3, lane, ya, yb);

    DS dsA = make_ds(p0a, p0b, lane);          // row y0-2
    DS dsB = make_ds(p1a, p1b, lane);          // row y0-1
    DS d0  = make_ds(p2a, p2b, lane);          // row y0
    DS d1  = make_ds(p3a, p3b, lane);          // row y0+1

    ER e_m;                                    // edge row y0-1 (zero pad at top)
    if (y0 > 0) e_m = make_edge(dsA, dsB, d0, lane);
    else        { e_m.el = e_m.eA = e_m.eB = e_m.er = 0.f; }
    ER e_c = make_edge(dsB, d0, d1, lane);     // edge row y0

    // last x row this strip needs:
    const int jlim       = (y0 + RSTRIP + 1 < HH) ? (y0 + RSTRIP + 1) : (HH - 1);
    const int steady_end = jlim - 3;           // r+4 <= jlim in steady loop

    // ---- steady state: branch-free, 2-deep prefetch, unrolled ----
    #pragma unroll 4
    for (int r = y0; r < steady_end; ++r) {
        // load row r+4 (consumed 2 iterations later) -- always in-range here
        const float2 nv = *(const float2*)(xp + (size_t)(r + 4) * WW + (lane << 1));

        DS d2 = make_ds(xa, xb, lane);         // row r+2
        ER e_p = make_edge(d0, d1, d2, lane);  // edge row r+1 (in-range here)

        float o0 = w0 * e_m.el + w1 * e_m.eA + w2 * e_m.eB
                 + w3 * e_c.el + w4 * e_c.eA + w5 * e_c.eB
                 + w6 * e_p.el + w7 * e_p.eA + w8 * e_p.eB;
        float o1 = w0 * e_m.eA + w1 * e_m.eB + w2 * e_m.er
                 + w3 * e_c.eA + w4 * e_c.eB + w5 * e_c.er
                 + w6 * e_p.eA + w7 * e_p.eB + w8 * e_p.er;
        o0 = fmaxf(o0 * inv + bias, 0.f);
        o1 = fmaxf(o1 * inv + bias, 0.f);
        *(float2*)(op + (size_t)r * WW + (lane << 1)) = make_float2(o0, o1);

        // rotate rings (named regs -> pure renames after unroll)
        d0 = d1; d1 = d2;
        e_m = e_c; e_c = e_p;
        xa = ya; xb = yb;
        ya = nv.x; yb = nv.y;
    }

    // ---- epilogue: last few rows (no more loads; bottom zero-pad) ----
    for (int r = steady_end; r < y0 + RSTRIP; ++r) {
        DS d2 = make_ds(xa, xb, lane);         // row r+2 (zeros if past jlim ring)
        ER e_p;
        if (r + 1 < HH) e_p = make_edge(d0, d1, d2, lane);
        else            { e_p.el = e_p.eA = e_p.eB = e_p.er = 0.f; }

        float o0 = w0 * e_m.el + w1 * e_m.eA + w2 * e_m.eB
                 + w3 * e_c.el + w4 * e_c.eA + w5 * e_c.eB
                 + w6 * e_p.el + w7 * e_p.eA + w8 * e_p.eB;
        float o1 = w0 * e_m.eA + w1 * e_m.eB + w2 * e_m.er
                 + w3 * e_c.eA + w4 * e_c.eB + w5 * e_c.er
                 + w6 * e_p.eA + w7 * e_p.eB + w8 * e_p.er;
        o0 = fmaxf(o0 * inv + bias, 0.f);
        o1 = fmaxf(o1 * inv + bias, 0.f);
        *(float2*)(op + (size_t)r * WW + (lane << 1)) = make_float2(o0, o1);

        d0 = d1; d1 = d2;
        e_m = e_c; e_c = e_p;
        xa = ya; xb = yb;
        ya = 0.f; yb = 0.f;                    // rows past jlim are zero pad
    }
}

extern "C" void kernel_launch(void* const* d_in, const int* in_sizes, int n_in,
                              void* d_out, int out_size, void* d_ws, size_t ws_size,
                              hipStream_t stream) {
    const float* x     = (const float*)d_in[0];
    const float* dw    = (const float*)d_in[1];
    const float* gamma = (const float*)d_in[2];
    const float* beta  = (const float*)d_in[3];
    const float* mean  = (const float*)d_in[4];
    const float* var   = (const float*)d_in[5];
    float* out = (float*)d_out;

    // 16*256 images * 2 strips = 8192 waves -> 2048 blocks of 4 waves
    const int nblocks = (BB * CC * NSTRIP) / 4;
    edge_attn_reg<<<nblocks, 256, 0, stream>>>(x, dw, gamma, beta, mean, var, out);
}